// Round 6
// baseline (185.010 us; speedup 1.0000x reference)
//
#include <hip/hip_runtime.h>

#define DD 6
#define FF 64
#define LN_EPS 1e-5f
#define GRID_BLOCKS 1024   // 256 CUs x 4 blocks/CU, co-resident per launch_bounds

typedef float f32x2 __attribute__((ext_vector_type(2)));

// DPP cross-lane move within a 16-lane row (VALU pipe, not DS).
// 0x140=row_mirror (l^15), 0x141=row_half_mirror (l^7),
// 0x4E=quad_perm[2,3,0,1] (l^2), 0xB1=quad_perm[1,0,3,2] (l^1).
template <int CTRL>
__device__ inline float dpp_mov(float x) {
    return __int_as_float(__builtin_amdgcn_update_dpp(
        0, __float_as_int(x), CTRL, 0xF, 0xF, true));
}

// Manual resident-grid barrier (counter pre-zeroed via hipMemsetAsync).
// Release on arrival orders phase-1 table stores (agent scope -> L2
// writeback); acquire fence after the spin makes them visible across XCDs.
__device__ inline void grid_barrier(unsigned* cnt) {
    __syncthreads();
    if (threadIdx.x == 0) {
        __hip_atomic_fetch_add(cnt, 1u, __ATOMIC_ACQ_REL,
                               __HIP_MEMORY_SCOPE_AGENT);
        while (__hip_atomic_load(cnt, __ATOMIC_RELAXED,
                                 __HIP_MEMORY_SCOPE_AGENT) < (unsigned)GRID_BLOCKS) {
            __builtin_amdgcn_s_sleep(2);
        }
    }
    __syncthreads();
    __builtin_amdgcn_fence(__ATOMIC_ACQUIRE, "agent");
}

// Fused single-launch kernel:
// Phase 1: per-entity partials tab[ent*8] = {S, SS, d0..d5},
//   S=sum_k m_k, SS=sum_k m_k^2, d_j=sum_k m_k*gamma[base+k]*W[base+k][j]
//   (base 0 nodes / 64 edges). 16-lane group handles pair (2p,2p+1),
//   grid-strided so the gamma*W hoist amortizes over ~4 pairs. DPP
//   butterfly leaves lane gl holding value index gl -> 64B store/group.
//   Block 0 threads 0..11 also produce gw_j / bw_j scalars.
// grid_barrier
// Phase 2: block-uniform grid-stride over super-blocks of 4x64 incidences
//   (one 64-group per wave). Gather 8 floats/side, combine, LN-fold,
//   sigmoid, LDS transpose with __syncthreads between write and read
//   (cross-lane LDS dependency — compiler won't order it otherwise),
//   f32x2 coalesced nt-stores.
__global__ __launch_bounds__(256, 4) void fused_kernel(
    const float* __restrict__ x, const float* __restrict__ e,
    const float* __restrict__ gamma, const float* __restrict__ beta,
    const float* __restrict__ W, const float* __restrict__ b,
    const int* __restrict__ row, const int* __restrict__ col,
    float* __restrict__ nodeT, float* __restrict__ edgeT,
    float* __restrict__ gwbw, unsigned* __restrict__ barrier_cnt,
    float* __restrict__ out, int N, int E, int nnz) {
    const int tid = threadIdx.x;

    if (blockIdx.x == 0 && tid < 12) {
        const int j = (tid < 6) ? tid : tid - 6;
        const float* g = (tid < 6) ? gamma : beta;
        float s = (tid < 6) ? 0.f : b[j];
        for (int k = 0; k < 2 * FF; ++k) s = fmaf(g[k], W[k * DD + j], s);
        gwbw[tid] = s;
    }

    const int gl = tid & 15;
    const int G = gridDim.x * (blockDim.x >> 4);
    const int g0 = blockIdx.x * (blockDim.x >> 4) + (tid >> 4);

    auto section = [&](const float* __restrict__ in, float* __restrict__ tab,
                       int kbase, int cnt) {
        const int pairs = (cnt + 1) >> 1;
        // gamma*W slice for this lane's 4 features (amortized over the loop).
        float gwl[4][6];
#pragma unroll
        for (int c = 0; c < 4; ++c) {
            const int k = kbase + 4 * gl + c;
            const float gk = gamma[k];
#pragma unroll
            for (int j = 0; j < 6; ++j) gwl[c][j] = gk * W[k * DD + j];
        }
        for (int p = g0; p < pairs; p += G) {
            const int A = 2 * p;
            const bool bval = (A + 1 < cnt);
            const int Bc = bval ? A + 1 : A;
            const float4* pa =
                reinterpret_cast<const float4*>(in + (size_t)A * (DD * FF)) + gl;
            const float4* pb =
                reinterpret_cast<const float4*>(in + (size_t)Bc * (DD * FF)) + gl;
            float4 sA = pa[0];
            float4 sB = pb[0];
#pragma unroll
            for (int d = 1; d < DD; ++d) {
                const float4 ta = pa[d * 16], tb = pb[d * 16];
                sA.x += ta.x; sA.y += ta.y; sA.z += ta.z; sA.w += ta.w;
                sB.x += tb.x; sB.y += tb.y; sB.z += tb.z; sB.w += tb.w;
            }
            const float inv6 = 1.0f / 6.0f;
            const float mA[4] = {sA.x * inv6, sA.y * inv6, sA.z * inv6, sA.w * inv6};
            const float mB[4] = {sB.x * inv6, sB.y * inv6, sB.z * inv6, sB.w * inv6};

            // v[0]=SA v[1]=SSA v[2..7]=dA[0..5] v[8]=SB v[9]=SSB v[10..15]=dB
            float v[16];
#pragma unroll
            for (int k = 0; k < 16; ++k) v[k] = 0.f;
#pragma unroll
            for (int c = 0; c < 4; ++c) {
                v[0] += mA[c];
                v[1] = fmaf(mA[c], mA[c], v[1]);
                v[8] += mB[c];
                v[9] = fmaf(mB[c], mB[c], v[9]);
#pragma unroll
                for (int j = 0; j < 6; ++j) {
                    v[2 + j]  = fmaf(mA[c], gwl[c][j], v[2 + j]);
                    v[10 + j] = fmaf(mB[c], gwl[c][j], v[10 + j]);
                }
            }
            float t[16];
            // stage 1: partner l^15, predicate bit3; live 16 -> 8
#pragma unroll
            for (int k = 0; k < 16; ++k) t[k] = dpp_mov<0x140>(v[k]);
            if (gl & 8) {
#pragma unroll
                for (int k = 0; k < 8; ++k) { v[k] = v[8 + k]; t[k] = t[8 + k]; }
            }
#pragma unroll
            for (int k = 0; k < 8; ++k) v[k] += t[k];
            // stage 2: partner l^7, predicate bit2; live 8 -> 4
#pragma unroll
            for (int k = 0; k < 8; ++k) t[k] = dpp_mov<0x141>(v[k]);
            if (gl & 4) {
#pragma unroll
                for (int k = 0; k < 4; ++k) { v[k] = v[4 + k]; t[k] = t[4 + k]; }
            }
#pragma unroll
            for (int k = 0; k < 4; ++k) v[k] += t[k];
            // stage 3: partner l^2, predicate bit1; live 4 -> 2
#pragma unroll
            for (int k = 0; k < 4; ++k) t[k] = dpp_mov<0x4E>(v[k]);
            if (gl & 2) { v[0] = v[2]; t[0] = t[2]; v[1] = v[3]; t[1] = t[3]; }
            v[0] += t[0]; v[1] += t[1];
            // stage 4: partner l^1, predicate bit0; live 2 -> 1
            t[0] = dpp_mov<0xB1>(v[0]);
            t[1] = dpp_mov<0xB1>(v[1]);
            if (gl & 1) { v[0] = v[1]; t[0] = t[1]; }
            const float r = v[0] + t[0];  // lane gl holds value index gl

            if (gl < 8) {
                tab[(size_t)A * 8 + gl] = r;            // contiguous 64B/group
            } else if (bval) {
                tab[(size_t)(A + 1) * 8 + (gl & 7)] = r;
            }
        }
    };
    section(x, nodeT, 0, N);
    section(e, edgeT, FF, E);

    grid_barrier(barrier_cnt);

    float gwv[12];
#pragma unroll
    for (int j = 0; j < 12; ++j) gwv[j] = gwbw[j];

    __shared__ float lds[4][64 * DD];
    const int wid = tid >> 6;
    const int l = tid & 63;
    const size_t lim = (size_t)nnz * DD;
    const int nblk = (nnz + 63) >> 6;      // 64-incidence groups

    // Block-uniform super-block loop: 4 groups per block iteration.
    for (int sb = blockIdx.x; sb * 4 < nblk; sb += gridDim.x) {
        const int bb = sb * 4 + wid;       // this wave's 64-group
        const bool active = (bb < nblk);
        if (active) {
            const int i = bb * 64 + l;
            const int ic = min(i, nnz - 1);
            const int rr = row[ic];
            const int cc = col[ic];
            const float4* np =
                reinterpret_cast<const float4*>(nodeT + (size_t)rr * 8);
            const float4* ep =
                reinterpret_cast<const float4*>(edgeT + (size_t)cc * 8);
            const float4 a0 = np[0], a1 = np[1];
            const float4 e0 = ep[0], e1 = ep[1];

            const float S  = a0.x + e0.x;
            const float SS = a0.y + e0.y;
            const float d[6] = {a0.z + e0.z, a0.w + e0.w, a1.x + e1.x,
                                a1.y + e1.y, a1.z + e1.z, a1.w + e1.w};

            const float mu  = S * (1.0f / 128.0f);
            const float var = fmaf(SS, 1.0f / 128.0f, -mu * mu);
            const float inv = rsqrtf(var + LN_EPS);

#pragma unroll
            for (int j = 0; j < 6; ++j) {
                const float pre = fmaf(inv, fmaf(-mu, gwv[j], d[j]), gwv[6 + j]);
                lds[wid][l * DD + j] = 1.0f / (1.0f + __expf(-pre));
            }
        }
        __syncthreads();   // order cross-lane LDS write -> read
        if (active) {
            const size_t base = (size_t)bb * (64 * DD);
#pragma unroll
            for (int j2 = 0; j2 < 3; ++j2) {
                const int f = j2 * 128 + 2 * l;        // bank-stride 2: free
                if (base + (size_t)f < lim) {          // lim even, f even
                    const f32x2 v2 = *reinterpret_cast<const f32x2*>(&lds[wid][f]);
                    __builtin_nontemporal_store(
                        v2, reinterpret_cast<f32x2*>(&out[base + (size_t)f]));
                }
            }
        }
        __syncthreads();   // protect reads from next iteration's writes
    }
}

extern "C" void kernel_launch(void* const* d_in, const int* in_sizes, int n_in,
                              void* d_out, int out_size, void* d_ws, size_t ws_size,
                              hipStream_t stream) {
    const float* x     = (const float*)d_in[0];
    const float* e     = (const float*)d_in[1];
    const int*   row   = (const int*)d_in[2];
    const int*   col   = (const int*)d_in[3];
    const float* gamma = (const float*)d_in[4];
    const float* beta  = (const float*)d_in[5];
    const float* W     = (const float*)d_in[6];
    const float* b     = (const float*)d_in[7];
    float* out = (float*)d_out;

    int N   = in_sizes[0] / (DD * FF);   // 100000 (element-count convention)
    int E   = in_sizes[1] / (DD * FF);   // 20000
    int NNZ = in_sizes[2];               // 1000000

    float* nodeT = (float*)d_ws;                   // N*8 f32 = 3.2 MB
    float* edgeT = nodeT + (size_t)N * 8;          // E*8 f32 = 0.64 MB
    float* gwbw  = edgeT + (size_t)E * 8;          // 12 f32 (pad to 20)
    unsigned* barrier_cnt = (unsigned*)(gwbw + 20);

    // Zero the barrier counter on-stream (graph-capture-legal, ~1-2 us),
    // since workspace poison is unknown between iterations.
    (void)hipMemsetAsync((void*)barrier_cnt, 0, sizeof(unsigned), stream);

    fused_kernel<<<GRID_BLOCKS, 256, 0, stream>>>(
        x, e, gamma, beta, W, b, row, col,
        nodeT, edgeT, gwbw, barrier_cnt, out, N, E, NNZ);
}

// Round 7
// 124.523 us; speedup vs baseline: 1.4857x; 1.4857x over previous
//
#include <hip/hip_runtime.h>

#define DD 6
#define FF 64
#define LN_EPS 1e-5f
#define GRID_BLOCKS 512    // 256 CUs x 2 blocks/CU, co-resident per launch_bounds

typedef float f32x2 __attribute__((ext_vector_type(2)));

// DPP cross-lane move within a 16-lane row (VALU pipe, not DS).
// 0x140=row_mirror (l^15), 0x141=row_half_mirror (l^7),
// 0x4E=quad_perm[2,3,0,1] (l^2), 0xB1=quad_perm[1,0,3,2] (l^1).
template <int CTRL>
__device__ inline float dpp_mov(float x) {
    return __int_as_float(__builtin_amdgcn_update_dpp(
        0, __float_as_int(x), CTRL, 0xF, 0xF, true));
}

// Manual resident-grid barrier (counter pre-zeroed via hipMemsetAsync).
// Release on arrival orders phase-1 table stores (agent scope -> L2
// writeback); acquire fence after the spin makes them visible across XCDs.
__device__ inline void grid_barrier(unsigned* cnt) {
    __syncthreads();
    if (threadIdx.x == 0) {
        __hip_atomic_fetch_add(cnt, 1u, __ATOMIC_ACQ_REL,
                               __HIP_MEMORY_SCOPE_AGENT);
        const unsigned want = gridDim.x;
        while (__hip_atomic_load(cnt, __ATOMIC_RELAXED,
                                 __HIP_MEMORY_SCOPE_AGENT) < want) {
            __builtin_amdgcn_s_sleep(2);
        }
    }
    __syncthreads();
    __builtin_amdgcn_fence(__ATOMIC_ACQUIRE, "agent");
}

// Fused single-launch kernel. launch_bounds(256,2): VGPR cap 256 so the
// phase-1 12x dwordx4 load batch stays fully in flight (48 VGPRs data +
// 24 gwl + 32 butterfly state). (256,4)'s 128-cap made the allocator
// roll/spill phase 1 -> 4x regression (R6: VGPR=48, VALUBusy 3.4%).
// Phase 1: per-entity partials tab[ent*8] = {S, SS, d0..d5} (grid-strided
//   pairs; DPP butterfly leaves lane gl holding value index gl).
// grid_barrier
// Phase 2: block-uniform super-blocks of 4x64 incidences; gather 8
//   floats/side, LN-fold, sigmoid, LDS transpose (+syncthreads), f32x2 NT
//   stores.
__global__ __launch_bounds__(256, 2) void fused_kernel(
    const float* __restrict__ x, const float* __restrict__ e,
    const float* __restrict__ gamma, const float* __restrict__ beta,
    const float* __restrict__ W, const float* __restrict__ b,
    const int* __restrict__ row, const int* __restrict__ col,
    float* __restrict__ nodeT, float* __restrict__ edgeT,
    float* __restrict__ gwbw, unsigned* __restrict__ barrier_cnt,
    float* __restrict__ out, int N, int E, int nnz) {
    const int tid = threadIdx.x;

    if (blockIdx.x == 0 && tid < 12) {
        const int j = (tid < 6) ? tid : tid - 6;
        const float* g = (tid < 6) ? gamma : beta;
        float s = (tid < 6) ? 0.f : b[j];
        for (int k = 0; k < 2 * FF; ++k) s = fmaf(g[k], W[k * DD + j], s);
        gwbw[tid] = s;
    }

    const int gl = tid & 15;
    const int G = gridDim.x * (blockDim.x >> 4);
    const int g0 = blockIdx.x * (blockDim.x >> 4) + (tid >> 4);

    auto section = [&](const float* __restrict__ in, float* __restrict__ tab,
                       int kbase, int cnt) {
        const int pairs = (cnt + 1) >> 1;
        // gamma*W slice for this lane's 4 features (loop-invariant hoist).
        float gwl[4][6];
#pragma unroll
        for (int c = 0; c < 4; ++c) {
            const int k = kbase + 4 * gl + c;
            const float gk = gamma[k];
#pragma unroll
            for (int j = 0; j < 6; ++j) gwl[c][j] = gk * W[k * DD + j];
        }
#pragma unroll 1
        for (int p = g0; p < pairs; p += G) {
            const int A = 2 * p;
            const bool bval = (A + 1 < cnt);
            const int Bc = bval ? A + 1 : A;
            const float4* pa =
                reinterpret_cast<const float4*>(in + (size_t)A * (DD * FF)) + gl;
            const float4* pb =
                reinterpret_cast<const float4*>(in + (size_t)Bc * (DD * FF)) + gl;
            // All 12 loads issued as one batch (needs the 256-VGPR cap).
            float4 va[DD], vb[DD];
#pragma unroll
            for (int d = 0; d < DD; ++d) { va[d] = pa[d * 16]; }
#pragma unroll
            for (int d = 0; d < DD; ++d) { vb[d] = pb[d * 16]; }

            float4 sA = va[0], sB = vb[0];
#pragma unroll
            for (int d = 1; d < DD; ++d) {
                sA.x += va[d].x; sA.y += va[d].y; sA.z += va[d].z; sA.w += va[d].w;
                sB.x += vb[d].x; sB.y += vb[d].y; sB.z += vb[d].z; sB.w += vb[d].w;
            }
            const float inv6 = 1.0f / 6.0f;
            const float mA[4] = {sA.x * inv6, sA.y * inv6, sA.z * inv6, sA.w * inv6};
            const float mB[4] = {sB.x * inv6, sB.y * inv6, sB.z * inv6, sB.w * inv6};

            // v[0]=SA v[1]=SSA v[2..7]=dA[0..5] v[8]=SB v[9]=SSB v[10..15]=dB
            float v[16];
#pragma unroll
            for (int k = 0; k < 16; ++k) v[k] = 0.f;
#pragma unroll
            for (int c = 0; c < 4; ++c) {
                v[0] += mA[c];
                v[1] = fmaf(mA[c], mA[c], v[1]);
                v[8] += mB[c];
                v[9] = fmaf(mB[c], mB[c], v[9]);
#pragma unroll
                for (int j = 0; j < 6; ++j) {
                    v[2 + j]  = fmaf(mA[c], gwl[c][j], v[2 + j]);
                    v[10 + j] = fmaf(mB[c], gwl[c][j], v[10 + j]);
                }
            }
            float t[16];
            // stage 1: partner l^15, predicate bit3; live 16 -> 8
#pragma unroll
            for (int k = 0; k < 16; ++k) t[k] = dpp_mov<0x140>(v[k]);
            if (gl & 8) {
#pragma unroll
                for (int k = 0; k < 8; ++k) { v[k] = v[8 + k]; t[k] = t[8 + k]; }
            }
#pragma unroll
            for (int k = 0; k < 8; ++k) v[k] += t[k];
            // stage 2: partner l^7, predicate bit2; live 8 -> 4
#pragma unroll
            for (int k = 0; k < 8; ++k) t[k] = dpp_mov<0x141>(v[k]);
            if (gl & 4) {
#pragma unroll
                for (int k = 0; k < 4; ++k) { v[k] = v[4 + k]; t[k] = t[4 + k]; }
            }
#pragma unroll
            for (int k = 0; k < 4; ++k) v[k] += t[k];
            // stage 3: partner l^2, predicate bit1; live 4 -> 2
#pragma unroll
            for (int k = 0; k < 4; ++k) t[k] = dpp_mov<0x4E>(v[k]);
            if (gl & 2) { v[0] = v[2]; t[0] = t[2]; v[1] = v[3]; t[1] = t[3]; }
            v[0] += t[0]; v[1] += t[1];
            // stage 4: partner l^1, predicate bit0; live 2 -> 1
            t[0] = dpp_mov<0xB1>(v[0]);
            t[1] = dpp_mov<0xB1>(v[1]);
            if (gl & 1) { v[0] = v[1]; t[0] = t[1]; }
            const float r = v[0] + t[0];  // lane gl holds value index gl

            if (gl < 8) {
                tab[(size_t)A * 8 + gl] = r;            // contiguous 64B/group
            } else if (bval) {
                tab[(size_t)(A + 1) * 8 + (gl & 7)] = r;
            }
        }
    };
    section(x, nodeT, 0, N);
    section(e, edgeT, FF, E);

    grid_barrier(barrier_cnt);

    float gwv[12];
#pragma unroll
    for (int j = 0; j < 12; ++j) gwv[j] = gwbw[j];

    __shared__ float lds[4][64 * DD];
    const int wid = tid >> 6;
    const int l = tid & 63;
    const size_t lim = (size_t)nnz * DD;
    const int nblk = (nnz + 63) >> 6;      // 64-incidence groups

    // Block-uniform super-block loop: 4 groups per block iteration.
#pragma unroll 1
    for (int sb = blockIdx.x; sb * 4 < nblk; sb += gridDim.x) {
        const int bb = sb * 4 + wid;       // this wave's 64-group
        const bool active = (bb < nblk);
        if (active) {
            const int i = bb * 64 + l;
            const int ic = min(i, nnz - 1);
            const int rr = row[ic];
            const int cc = col[ic];
            const float4* np =
                reinterpret_cast<const float4*>(nodeT + (size_t)rr * 8);
            const float4* ep =
                reinterpret_cast<const float4*>(edgeT + (size_t)cc * 8);
            const float4 a0 = np[0], a1 = np[1];
            const float4 e0 = ep[0], e1 = ep[1];

            const float S  = a0.x + e0.x;
            const float SS = a0.y + e0.y;
            const float d[6] = {a0.z + e0.z, a0.w + e0.w, a1.x + e1.x,
                                a1.y + e1.y, a1.z + e1.z, a1.w + e1.w};

            const float mu  = S * (1.0f / 128.0f);
            const float var = fmaf(SS, 1.0f / 128.0f, -mu * mu);
            const float inv = rsqrtf(var + LN_EPS);

#pragma unroll
            for (int j = 0; j < 6; ++j) {
                const float pre = fmaf(inv, fmaf(-mu, gwv[j], d[j]), gwv[6 + j]);
                lds[wid][l * DD + j] = 1.0f / (1.0f + __expf(-pre));
            }
        }
        __syncthreads();   // order cross-lane LDS write -> read
        if (active) {
            const size_t base = (size_t)bb * (64 * DD);
#pragma unroll
            for (int j2 = 0; j2 < 3; ++j2) {
                const int f = j2 * 128 + 2 * l;        // bank-stride 2: free
                if (base + (size_t)f < lim) {          // lim even, f even
                    const f32x2 v2 = *reinterpret_cast<const f32x2*>(&lds[wid][f]);
                    __builtin_nontemporal_store(
                        v2, reinterpret_cast<f32x2*>(&out[base + (size_t)f]));
                }
            }
        }
        __syncthreads();   // protect reads from next iteration's writes
    }
}

extern "C" void kernel_launch(void* const* d_in, const int* in_sizes, int n_in,
                              void* d_out, int out_size, void* d_ws, size_t ws_size,
                              hipStream_t stream) {
    const float* x     = (const float*)d_in[0];
    const float* e     = (const float*)d_in[1];
    const int*   row   = (const int*)d_in[2];
    const int*   col   = (const int*)d_in[3];
    const float* gamma = (const float*)d_in[4];
    const float* beta  = (const float*)d_in[5];
    const float* W     = (const float*)d_in[6];
    const float* b     = (const float*)d_in[7];
    float* out = (float*)d_out;

    int N   = in_sizes[0] / (DD * FF);   // 100000 (element-count convention)
    int E   = in_sizes[1] / (DD * FF);   // 20000
    int NNZ = in_sizes[2];               // 1000000

    float* nodeT = (float*)d_ws;                   // N*8 f32 = 3.2 MB
    float* edgeT = nodeT + (size_t)N * 8;          // E*8 f32 = 0.64 MB
    float* gwbw  = edgeT + (size_t)E * 8;          // 12 f32 (pad to 20)
    unsigned* barrier_cnt = (unsigned*)(gwbw + 20);

    // Zero the barrier counter on-stream (graph-capture-legal, ~1-2 us),
    // since workspace poison is unknown between iterations.
    (void)hipMemsetAsync((void*)barrier_cnt, 0, sizeof(unsigned), stream);

    fused_kernel<<<GRID_BLOCKS, 256, 0, stream>>>(
        x, e, gamma, beta, W, b, row, col,
        nodeT, edgeT, gwbw, barrier_cnt, out, N, E, NNZ);
}

// Round 8
// 52.721 us; speedup vs baseline: 3.5092x; 2.3619x over previous
//
#include <hip/hip_runtime.h>

#define DD 6
#define FF 64
#define LN_EPS 1e-5f

typedef float f32x2 __attribute__((ext_vector_type(2)));

// DPP cross-lane move within a 16-lane row (VALU pipe, not DS).
// 0x140=row_mirror (l^15), 0x141=row_half_mirror (l^7),
// 0x4E=quad_perm[2,3,0,1] (l^2), 0xB1=quad_perm[1,0,3,2] (l^1).
template <int CTRL>
__device__ inline float dpp_mov(float x) {
    return __int_as_float(__builtin_amdgcn_update_dpp(
        0, __float_as_int(x), CTRL, 0xF, 0xF, true));
}

// Pass 1: fused stalk-mean + per-entity LN/matvec partials.
// tab[ent*8] = {S, SS, d0..d5} with S=sum_k m_k, SS=sum_k m_k^2,
// d_j = sum_k m_k*gamma[base+k]*W[base+k][j] (base 0 nodes / 64 edges).
// 16-lane group handles entity pair (A=2p, B=2p+1); lane gl owns feats
// 4gl..4gl+3. DPP butterfly leaves lane gl holding value index gl
// (0..7 = A, 8..15 = B) -> contiguous 64B store per group.
// One-shot (one pair per group, no grid-stride): straight-line body lets
// the allocator batch all 12 dwordx4 loads (~110 VGPR). The persistent
// grid-stride variant (R6/R7) compiled to VGPR=48 with serialized loads
// and ran 3x slower — do not re-fuse without disasm evidence.
// Block 0 threads 0..11 also compute gw_j / bw_j scalars.
__global__ __launch_bounds__(256) void entity_kernel(
    const float* __restrict__ x, const float* __restrict__ e,
    const float* __restrict__ gamma, const float* __restrict__ beta,
    const float* __restrict__ W, const float* __restrict__ b,
    float* __restrict__ nodeT, float* __restrict__ edgeT,
    float* __restrict__ gwbw, int N, int E) {
    if (blockIdx.x == 0 && threadIdx.x < 12) {
        const int t = threadIdx.x;
        const int j = (t < 6) ? t : t - 6;
        const float* g = (t < 6) ? gamma : beta;
        float s = (t < 6) ? 0.f : b[j];
        for (int k = 0; k < 2 * FF; ++k) s = fmaf(g[k], W[k * DD + j], s);
        gwbw[t] = s;
    }

    const int gl = threadIdx.x & 15;
    const int nodePairs = (N + 1) >> 1;
    const int edgePairs = (E + 1) >> 1;
    const int p = blockIdx.x * 16 + (threadIdx.x >> 4);
    if (p >= nodePairs + edgePairs) return;

    const float* in; float* tab; int A, last, kbase;
    if (p < nodePairs) {
        in = x; tab = nodeT; A = 2 * p; last = N - 1; kbase = 0;
    } else {
        in = e; tab = edgeT; A = 2 * (p - nodePairs); last = E - 1; kbase = FF;
    }
    const int B = A + 1;
    const bool bval = (B <= last);
    const int Bc = bval ? B : A;

    // Issue the 12 float4 data loads first to overlap the gamma*W hoist.
    const float4* pa = reinterpret_cast<const float4*>(in + (size_t)A * (DD * FF)) + gl;
    const float4* pb = reinterpret_cast<const float4*>(in + (size_t)Bc * (DD * FF)) + gl;
    float4 va[DD], vb[DD];
#pragma unroll
    for (int d = 0; d < DD; ++d) { va[d] = pa[d * 16]; vb[d] = pb[d * 16]; }

    float gwl[4][6];
#pragma unroll
    for (int c = 0; c < 4; ++c) {
        const int k = kbase + 4 * gl + c;
        const float gk = gamma[k];
#pragma unroll
        for (int j = 0; j < 6; ++j) gwl[c][j] = gk * W[k * DD + j];
    }

    float mA[4], mB[4];
    {
        float s0 = 0.f, s1 = 0.f, s2 = 0.f, s3 = 0.f;
        float u0 = 0.f, u1 = 0.f, u2 = 0.f, u3 = 0.f;
#pragma unroll
        for (int d = 0; d < DD; ++d) {
            s0 += va[d].x; s1 += va[d].y; s2 += va[d].z; s3 += va[d].w;
            u0 += vb[d].x; u1 += vb[d].y; u2 += vb[d].z; u3 += vb[d].w;
        }
        const float inv6 = 1.0f / 6.0f;
        mA[0] = s0 * inv6; mA[1] = s1 * inv6; mA[2] = s2 * inv6; mA[3] = s3 * inv6;
        mB[0] = u0 * inv6; mB[1] = u1 * inv6; mB[2] = u2 * inv6; mB[3] = u3 * inv6;
    }

    // v[0]=SA v[1]=SSA v[2..7]=dA[0..5] v[8]=SB v[9]=SSB v[10..15]=dB
    float v[16];
#pragma unroll
    for (int k = 0; k < 16; ++k) v[k] = 0.f;
#pragma unroll
    for (int c = 0; c < 4; ++c) {
        v[0] += mA[c];
        v[1] = fmaf(mA[c], mA[c], v[1]);
        v[8] += mB[c];
        v[9] = fmaf(mB[c], mB[c], v[9]);
#pragma unroll
        for (int j = 0; j < 6; ++j) {
            v[2 + j]  = fmaf(mA[c], gwl[c][j], v[2 + j]);
            v[10 + j] = fmaf(mB[c], gwl[c][j], v[10 + j]);
        }
    }

    float t[16];
    // stage 1: partner l^15 (row_mirror), predicate bit3; live 16 -> 8
#pragma unroll
    for (int k = 0; k < 16; ++k) t[k] = dpp_mov<0x140>(v[k]);
    if (gl & 8) {
#pragma unroll
        for (int k = 0; k < 8; ++k) { v[k] = v[8 + k]; t[k] = t[8 + k]; }
    }
#pragma unroll
    for (int k = 0; k < 8; ++k) v[k] += t[k];
    // stage 2: partner l^7 (row_half_mirror), predicate bit2; live 8 -> 4
#pragma unroll
    for (int k = 0; k < 8; ++k) t[k] = dpp_mov<0x141>(v[k]);
    if (gl & 4) {
#pragma unroll
        for (int k = 0; k < 4; ++k) { v[k] = v[4 + k]; t[k] = t[4 + k]; }
    }
#pragma unroll
    for (int k = 0; k < 4; ++k) v[k] += t[k];
    // stage 3: partner l^2 (quad_perm[2,3,0,1]), predicate bit1; live 4 -> 2
#pragma unroll
    for (int k = 0; k < 4; ++k) t[k] = dpp_mov<0x4E>(v[k]);
    if (gl & 2) { v[0] = v[2]; t[0] = t[2]; v[1] = v[3]; t[1] = t[3]; }
    v[0] += t[0]; v[1] += t[1];
    // stage 4: partner l^1 (quad_perm[1,0,3,2]), predicate bit0; live 2 -> 1
    t[0] = dpp_mov<0xB1>(v[0]);
    t[1] = dpp_mov<0xB1>(v[1]);
    if (gl & 1) { v[0] = v[1]; t[0] = t[1]; }
    const float r = v[0] + t[0];   // lane gl holds total of value index gl

    if (gl < 8) {
        tab[(size_t)A * 8 + gl] = r;
    } else if (bval) {
        tab[(size_t)B * 8 + (gl & 7)] = r;
    }
}

// Pass 2: one thread per incidence (one-shot, high occupancy). Gather 8
// floats/side (node table 3.2 MB + edge table 0.64 MB -> L2-resident),
// combine, LN-fold, sigmoid, LDS transpose, f32x2 coalesced NT stores.
__global__ __launch_bounds__(256) void incidence_kernel(
    const float* __restrict__ nodeT, const float* __restrict__ edgeT,
    const int* __restrict__ row, const int* __restrict__ col,
    const float* __restrict__ gwbw, float* __restrict__ out, int nnz) {
    __shared__ float lds[4][64 * DD];
    const int wid = threadIdx.x >> 6;
    const int l = threadIdx.x & 63;
    const int i = blockIdx.x * blockDim.x + threadIdx.x;
    const int ic = min(i, nnz - 1);
    const int rr = row[ic];
    const int cc = col[ic];
    const float4* np = reinterpret_cast<const float4*>(nodeT + (size_t)rr * 8);
    const float4* ep = reinterpret_cast<const float4*>(edgeT + (size_t)cc * 8);
    const float4 a0 = np[0], a1 = np[1];
    const float4 b0 = ep[0], b1 = ep[1];

    const float S  = a0.x + b0.x;
    const float SS = a0.y + b0.y;
    const float d[6] = {a0.z + b0.z, a0.w + b0.w, a1.x + b1.x,
                        a1.y + b1.y, a1.z + b1.z, a1.w + b1.w};

    const float mu  = S * (1.0f / 128.0f);
    const float var = fmaf(SS, 1.0f / 128.0f, -mu * mu);
    const float inv = rsqrtf(var + LN_EPS);

#pragma unroll
    for (int j = 0; j < 6; ++j) {
        const float pre = fmaf(inv, fmaf(-mu, gwbw[j], d[j]), gwbw[6 + j]);
        lds[wid][l * DD + j] = 1.0f / (1.0f + __expf(-pre));
    }
    __syncthreads();   // cross-lane LDS write -> read ordering
    const size_t base = (size_t)(blockIdx.x * blockDim.x + wid * 64) * DD;
    const size_t lim = (size_t)nnz * DD;
#pragma unroll
    for (int j2 = 0; j2 < 3; ++j2) {
        const int f = j2 * 128 + 2 * l;                // bank-stride 2: free
        if (base + (size_t)f < lim) {                  // lim even, f even
            const f32x2 v2 = *reinterpret_cast<const f32x2*>(&lds[wid][f]);
            __builtin_nontemporal_store(
                v2, reinterpret_cast<f32x2*>(&out[base + (size_t)f]));
        }
    }
}

extern "C" void kernel_launch(void* const* d_in, const int* in_sizes, int n_in,
                              void* d_out, int out_size, void* d_ws, size_t ws_size,
                              hipStream_t stream) {
    const float* x     = (const float*)d_in[0];
    const float* e     = (const float*)d_in[1];
    const int*   row   = (const int*)d_in[2];
    const int*   col   = (const int*)d_in[3];
    const float* gamma = (const float*)d_in[4];
    const float* beta  = (const float*)d_in[5];
    const float* W     = (const float*)d_in[6];
    const float* b     = (const float*)d_in[7];
    float* out = (float*)d_out;

    const int N   = in_sizes[0] / (DD * FF);   // 100000 (element-count convention)
    const int E   = in_sizes[1] / (DD * FF);   // 20000
    const int NNZ = in_sizes[2];               // 1000000

    float* nodeT = (float*)d_ws;               // N*8 f32 = 3.2 MB
    float* edgeT = nodeT + (size_t)N * 8;      // E*8 f32 = 0.64 MB
    float* gwbw  = edgeT + (size_t)E * 8;      // 12 f32

    {
        const int totalPairs = ((N + 1) >> 1) + ((E + 1) >> 1);
        const int blocks = (totalPairs + 15) / 16;     // 3750
        entity_kernel<<<blocks, 256, 0, stream>>>(x, e, gamma, beta, W, b,
                                                  nodeT, edgeT, gwbw, N, E);
    }
    {
        const int blocks = (NNZ + 255) / 256;          // 3907
        incidence_kernel<<<blocks, 256, 0, stream>>>(nodeT, edgeT, row, col,
                                                     gwbw, out, NNZ);
    }
}